// Round 9
// baseline (43.601 us; speedup 1.0000x reference)
//
#include <hip/hip_runtime.h>
#include <math.h>

#define BB 4
#define SS 4096
#define DK 5
#define NT 256
// (1/sqrt(5)) * log2(e) folded into all score terms so p = v_exp_f32(score)
#define LAM (0.44721359549995793f * 1.4426950408889634f)

typedef float v2f __attribute__((ext_vector_type(2)));

__device__ __forceinline__ float fast_exp2(float x) {
#if __has_builtin(__builtin_amdgcn_exp2f)
    return __builtin_amdgcn_exp2f(x);
#else
    float r; asm("v_exp_f32 %0, %1" : "=v"(r) : "v"(x)); return r;
#endif
}

// Packed fp32: compiler selects v_pk_fma_f32 on gfx90a+ for <2 x float> fma.
__device__ __forceinline__ v2f pk_fma(v2f a, v2f b, v2f c) {
    return __builtin_elementwise_fma(a, b, c);
}

// ---------------------------------------------------------------------------
// Kernel 1: K' = [x0,x1,x2,g], g = LAM*(Wk^T bq)·x  (bq cross-term; per-row
// bias terms cancel in numerator/denominator). V^T = [B][5][S].
// ---------------------------------------------------------------------------
__global__ __launch_bounds__(NT) void proj_kv(
    const float* __restrict__ x,
    const float* __restrict__ Wk, const float* __restrict__ bq,
    const float* __restrict__ Wv, const float* __restrict__ bv,
    float* __restrict__ Kt, float* __restrict__ Vt)
{
    int gid = blockIdx.x * NT + threadIdx.x;
    if (gid >= BB * SS) return;
    int b = gid >> 12;
    int s = gid & (SS - 1);
    float x0 = x[gid * 3 + 0];
    float x1 = x[gid * 3 + 1];
    float x2 = x[gid * 3 + 2];

    float u0 = 0.f, u1 = 0.f, u2 = 0.f;   // u = Wk^T bq
#pragma unroll
    for (int d = 0; d < DK; ++d) {
        float bqd = bq[d];
        u0 = fmaf(Wk[d * 3 + 0], bqd, u0);
        u1 = fmaf(Wk[d * 3 + 1], bqd, u1);
        u2 = fmaf(Wk[d * 3 + 2], bqd, u2);
    }
    float g = LAM * (u0 * x0 + u1 * x1 + u2 * x2);

    float* KtB = Kt + (size_t)b * 4 * SS;
    KtB[0 * SS + s] = x0;
    KtB[1 * SS + s] = x1;
    KtB[2 * SS + s] = x2;
    KtB[3 * SS + s] = g;

#pragma unroll
    for (int d = 0; d < DK; ++d) {
        float vv = fmaf(Wv[d * 3 + 0], x0, fmaf(Wv[d * 3 + 1], x1, fmaf(Wv[d * 3 + 2], x2, bv[d])));
        Vt[((size_t)b * DK + d) * SS + s] = vv;
    }
}

// ---------------------------------------------------------------------------
// Kernel 2: attention, NO LDS / NO BARRIERS. Kt+Vt = 655 KB fits in every
// XCD's 4 MB L2, so LDS staging was pure overhead (barriers + LDS pipe +
// 36 KB footprint). Each lane reads its own 4-key chunk directly from L2
// (coalesced float4 per plane). Every wave owns 2 low + 2 high (mirror)
// rows -> uniform work per wave/block; waves free-run.
// score = a_q·x_k + g_k (pre-scaled), p = exp2(score).
// Denominator: all keys; numerator: keys <= row (mask-after-softmax).
// ---------------------------------------------------------------------------
__global__ __launch_bounds__(NT) void attn(
    const float* __restrict__ x,
    const float* __restrict__ Wq, const float* __restrict__ Wk,
    const float* __restrict__ Kt, const float* __restrict__ Vt,
    float* __restrict__ out)
{
    const int tid = threadIdx.x;
    const int sub = tid & 63;
    const int wave = tid >> 6;

    const int b = blockIdx.x >> 8;
    const int i = blockIdx.x & 255;
    const int lo0 = i * 8 + wave * 2;          // rows: lo0, lo0+1, hi0, hi0+1
    const int hi0 = (511 - i) * 8 + wave * 2;
    const int rows[4] = {lo0, lo0 + 1, hi0, hi0 + 1};

    // M = Wq^T Wk (3x3), uniform
    float M00=0,M01=0,M02=0,M10=0,M11=0,M12=0,M20=0,M21=0,M22=0;
#pragma unroll
    for (int d = 0; d < DK; ++d) {
        float q0 = Wq[d*3+0], q1 = Wq[d*3+1], q2 = Wq[d*3+2];
        float k0 = Wk[d*3+0], k1 = Wk[d*3+1], k2 = Wk[d*3+2];
        M00 = fmaf(q0,k0,M00); M01 = fmaf(q0,k1,M01); M02 = fmaf(q0,k2,M02);
        M10 = fmaf(q1,k0,M10); M11 = fmaf(q1,k1,M11); M12 = fmaf(q1,k2,M12);
        M20 = fmaf(q2,k0,M20); M21 = fmaf(q2,k1,M21); M22 = fmaf(q2,k2,M22);
    }

    // per-row a (broadcast into both packed halves)
    v2f a2[4][3];
#pragma unroll
    for (int r = 0; r < 4; ++r) {
        const float* xr = &x[((size_t)b * SS + rows[r]) * 3];
        float x0 = xr[0], x1 = xr[1], x2 = xr[2];
        float av0 = LAM * (x0*M00 + x1*M10 + x2*M20);
        float av1 = LAM * (x0*M01 + x1*M11 + x2*M21);
        float av2 = LAM * (x0*M02 + x1*M12 + x2*M22);
        a2[r][0] = (v2f){av0, av0};
        a2[r][1] = (v2f){av1, av1};
        a2[r][2] = (v2f){av2, av2};
    }

    v2f l2[4];
    v2f acc2[4][DK];
#pragma unroll
    for (int r = 0; r < 4; ++r) {
        l2[r] = (v2f){0.f, 0.f};
#pragma unroll
        for (int d = 0; d < DK; ++d) acc2[r][d] = (v2f){0.f, 0.f};
    }

    const float* KtB = Kt + (size_t)b * 4 * SS;
    const float* VtB = Vt + (size_t)b * DK * SS;

    for (int c = 0; c < SS / 256; ++c) {       // 16 chunks of 256 keys
        const int cstart = c * 256;            // wave-uniform chunk bounds
        const int cend   = cstart + 255;
        const int kbase  = cstart + sub * 4;   // this lane's 4 keys

        float4 kt0 = *(const float4*)&KtB[0 * SS + kbase];
        float4 kt1 = *(const float4*)&KtB[1 * SS + kbase];
        float4 kt2 = *(const float4*)&KtB[2 * SS + kbase];
        float4 kt3 = *(const float4*)&KtB[3 * SS + kbase];

        if (cstart <= hi0 + 1) {
            // V loaded and consumed in the same scope (spill-safe, R8 lesson)
            float4 vt0 = *(const float4*)&VtB[0 * SS + kbase];
            float4 vt1 = *(const float4*)&VtB[1 * SS + kbase];
            float4 vt2 = *(const float4*)&VtB[2 * SS + kbase];
            float4 vt3 = *(const float4*)&VtB[3 * SS + kbase];
            float4 vt4 = *(const float4*)&VtB[4 * SS + kbase];
#pragma unroll
            for (int h = 0; h < 2; ++h) {      // 2 keys per half
                const int kgh = kbase + h * 2;
                v2f k0 = ((v2f*)&kt0)[h];
                v2f k1 = ((v2f*)&kt1)[h];
                v2f k2 = ((v2f*)&kt2)[h];
                v2f g  = ((v2f*)&kt3)[h];
                v2f v0 = ((v2f*)&vt0)[h];
                v2f v1 = ((v2f*)&vt1)[h];
                v2f v2 = ((v2f*)&vt2)[h];
                v2f v3 = ((v2f*)&vt3)[h];
                v2f v4 = ((v2f*)&vt4)[h];
#pragma unroll
                for (int r = 0; r < 4; ++r) {
                    const int row = rows[r];
                    v2f sc = pk_fma(a2[r][0], k0,
                             pk_fma(a2[r][1], k1,
                             pk_fma(a2[r][2], k2, g)));
                    v2f p;
                    p.x = fast_exp2(sc.x); p.y = fast_exp2(sc.y);
                    l2[r] += p;
                    if (cend <= row) {          // full accumulate
                        acc2[r][0] = pk_fma(p, v0, acc2[r][0]);
                        acc2[r][1] = pk_fma(p, v1, acc2[r][1]);
                        acc2[r][2] = pk_fma(p, v2, acc2[r][2]);
                        acc2[r][3] = pk_fma(p, v3, acc2[r][3]);
                        acc2[r][4] = pk_fma(p, v4, acc2[r][4]);
                    } else if (cstart <= row) { // boundary: masked
                        v2f pm;
                        pm.x = (kgh + 0 <= row) ? p.x : 0.f;
                        pm.y = (kgh + 1 <= row) ? p.y : 0.f;
                        acc2[r][0] = pk_fma(pm, v0, acc2[r][0]);
                        acc2[r][1] = pk_fma(pm, v1, acc2[r][1]);
                        acc2[r][2] = pk_fma(pm, v2, acc2[r][2]);
                        acc2[r][3] = pk_fma(pm, v3, acc2[r][3]);
                        acc2[r][4] = pk_fma(pm, v4, acc2[r][4]);
                    }
                    // else: future-only for this row -> denominator only
                }
            }
        } else {
            // denominator-only chunk for all 4 rows
#pragma unroll
            for (int h = 0; h < 2; ++h) {
                v2f k0 = ((v2f*)&kt0)[h];
                v2f k1 = ((v2f*)&kt1)[h];
                v2f k2 = ((v2f*)&kt2)[h];
                v2f g  = ((v2f*)&kt3)[h];
#pragma unroll
                for (int r = 0; r < 4; ++r) {
                    v2f sc = pk_fma(a2[r][0], k0,
                             pk_fma(a2[r][1], k1,
                             pk_fma(a2[r][2], k2, g)));
                    v2f p;
                    p.x = fast_exp2(sc.x); p.y = fast_exp2(sc.y);
                    l2[r] += p;
                }
            }
        }
    }

    // fold packed halves, then butterfly-reduce across the 64 key-split lanes
#pragma unroll
    for (int r = 0; r < 4; ++r) {
        float lr = l2[r].x + l2[r].y;
        float a0 = acc2[r][0].x + acc2[r][0].y;
        float a1 = acc2[r][1].x + acc2[r][1].y;
        float a2_ = acc2[r][2].x + acc2[r][2].y;
        float a3 = acc2[r][3].x + acc2[r][3].y;
        float a4 = acc2[r][4].x + acc2[r][4].y;
#pragma unroll
        for (int off = 32; off >= 1; off >>= 1) {
            lr  += __shfl_xor(lr, off);
            a0  += __shfl_xor(a0, off);
            a1  += __shfl_xor(a1, off);
            a2_ += __shfl_xor(a2_, off);
            a3  += __shfl_xor(a3, off);
            a4  += __shfl_xor(a4, off);
        }
        if (sub < DK) {
            float av = sub == 0 ? a0 : sub == 1 ? a1 : sub == 2 ? a2_ : sub == 3 ? a3 : a4;
            out[((size_t)b * SS + rows[r]) * DK + sub] = av / lr;
        }
    }
}

extern "C" void kernel_launch(void* const* d_in, const int* in_sizes, int n_in,
                              void* d_out, int out_size, void* d_ws, size_t ws_size,
                              hipStream_t stream) {
    const float* x  = (const float*)d_in[0];
    const float* Wq = (const float*)d_in[1];
    const float* bq = (const float*)d_in[2];
    const float* Wk = (const float*)d_in[3];
    const float* Wv = (const float*)d_in[5];
    const float* bv = (const float*)d_in[6];
    float* outp = (float*)d_out;

    float* Kt = (float*)d_ws;                       // [B][4][S]  (x0,x1,x2,g)
    float* Vt = Kt + (size_t)BB * 4 * SS;           // [B][5][S]

    proj_kv<<<(BB * SS + NT - 1) / NT, NT, 0, stream>>>(x, Wk, bq, Wv, bv, Kt, Vt);
    attn<<<BB * (SS / 16), NT, 0, stream>>>(x, Wq, Wk, Kt, Vt, outp);
}

// Round 10
// 39.445 us; speedup vs baseline: 1.1054x; 1.1054x over previous
//
#include <hip/hip_runtime.h>
#include <math.h>

#define BB 4
#define SS 4096
#define DK 5
#define TK 1024
#define NT 256
// (1/sqrt(5)) * log2(e) folded into all score terms so p = v_exp_f32(score)
#define LAM (0.44721359549995793f * 1.4426950408889634f)

typedef float v2f __attribute__((ext_vector_type(2)));

__device__ __forceinline__ float fast_exp2(float x) {
#if __has_builtin(__builtin_amdgcn_exp2f)
    return __builtin_amdgcn_exp2f(x);
#else
    float r; asm("v_exp_f32 %0, %1" : "=v"(r) : "v"(x)); return r;
#endif
}

// Packed fp32: compiler selects v_pk_fma_f32 on gfx90a+ for <2 x float> fma.
__device__ __forceinline__ v2f pk_fma(v2f a, v2f b, v2f c) {
    return __builtin_elementwise_fma(a, b, c);
}

// async global->LDS, 16B per lane (dest lane-contiguous)
#define GLOAD16(gp, lp)                                                        \
    __builtin_amdgcn_global_load_lds(                                          \
        (const __attribute__((address_space(1))) unsigned int*)(gp),           \
        (__attribute__((address_space(3))) unsigned int*)(lp), 16, 0, 0)

// ---------------------------------------------------------------------------
// Kernel 1: K' = [x0,x1,x2,g], g = LAM*(Wk^T bq)·x  (bq cross-term; per-row
// bias terms cancel in numerator/denominator). V^T = [B][5][S].
// ---------------------------------------------------------------------------
__global__ __launch_bounds__(NT) void proj_kv(
    const float* __restrict__ x,
    const float* __restrict__ Wk, const float* __restrict__ bq,
    const float* __restrict__ Wv, const float* __restrict__ bv,
    float* __restrict__ Kt, float* __restrict__ Vt)
{
    int gid = blockIdx.x * NT + threadIdx.x;
    if (gid >= BB * SS) return;
    int b = gid >> 12;
    int s = gid & (SS - 1);
    float x0 = x[gid * 3 + 0];
    float x1 = x[gid * 3 + 1];
    float x2 = x[gid * 3 + 2];

    float u0 = 0.f, u1 = 0.f, u2 = 0.f;   // u = Wk^T bq
#pragma unroll
    for (int d = 0; d < DK; ++d) {
        float bqd = bq[d];
        u0 = fmaf(Wk[d * 3 + 0], bqd, u0);
        u1 = fmaf(Wk[d * 3 + 1], bqd, u1);
        u2 = fmaf(Wk[d * 3 + 2], bqd, u2);
    }
    float g = LAM * (u0 * x0 + u1 * x1 + u2 * x2);

    float* KtB = Kt + (size_t)b * 4 * SS;
    KtB[0 * SS + s] = x0;
    KtB[1 * SS + s] = x1;
    KtB[2 * SS + s] = x2;
    KtB[3 * SS + s] = g;

#pragma unroll
    for (int d = 0; d < DK; ++d) {
        float vv = fmaf(Wv[d * 3 + 0], x0, fmaf(Wv[d * 3 + 1], x1, fmaf(Wv[d * 3 + 2], x2, bv[d])));
        Vt[((size_t)b * DK + d) * SS + s] = vv;
    }
}

// ---------------------------------------------------------------------------
// Kernel 2: attention. Combines ALL three proven-safe properties:
//  - balanced rows (every wave: 2 low + 2 high mirror rows -> uniform work
//    per wave AND per block, no barrier stranding, no tail),
//  - ds_read_b128 chunk loads (9 float4/chunk; halves are register slices),
//  - __launch_bounds__(256,4) for 4 waves/SIMD latency hiding.
// V loaded and consumed in the same wave-uniform scope (spill-safe).
// score = a_q·x_k + g_k (pre-scaled), p = exp2(score).
// Denominator: all keys; numerator: keys <= row (mask-after-softmax).
// ---------------------------------------------------------------------------
__global__ __launch_bounds__(NT, 4) void attn(
    const float* __restrict__ x,
    const float* __restrict__ Wq, const float* __restrict__ Wk,
    const float* __restrict__ Kt, const float* __restrict__ Vt,
    float* __restrict__ out)
{
    __shared__ float kls[4][TK];
    __shared__ float vls[DK][TK];

    const int tid = threadIdx.x;
    const int sub = tid & 63;
    const int wave = tid >> 6;

    const int b = blockIdx.x >> 8;
    const int i = blockIdx.x & 255;
    const int lo0 = i * 8 + wave * 2;          // rows: lo0, lo0+1, hi0, hi0+1
    const int hi0 = (511 - i) * 8 + wave * 2;
    const int rowMaxBlk = (511 - i) * 8 + 7;
    const int rows[4] = {lo0, lo0 + 1, hi0, hi0 + 1};

    // M = Wq^T Wk (3x3), uniform
    float M00=0,M01=0,M02=0,M10=0,M11=0,M12=0,M20=0,M21=0,M22=0;
#pragma unroll
    for (int d = 0; d < DK; ++d) {
        float q0 = Wq[d*3+0], q1 = Wq[d*3+1], q2 = Wq[d*3+2];
        float k0 = Wk[d*3+0], k1 = Wk[d*3+1], k2 = Wk[d*3+2];
        M00 = fmaf(q0,k0,M00); M01 = fmaf(q0,k1,M01); M02 = fmaf(q0,k2,M02);
        M10 = fmaf(q1,k0,M10); M11 = fmaf(q1,k1,M11); M12 = fmaf(q1,k2,M12);
        M20 = fmaf(q2,k0,M20); M21 = fmaf(q2,k1,M21); M22 = fmaf(q2,k2,M22);
    }

    // per-row a (broadcast into both packed halves)
    v2f a2[4][3];
#pragma unroll
    for (int r = 0; r < 4; ++r) {
        const float* xr = &x[((size_t)b * SS + rows[r]) * 3];
        float x0 = xr[0], x1 = xr[1], x2 = xr[2];
        float av0 = LAM * (x0*M00 + x1*M10 + x2*M20);
        float av1 = LAM * (x0*M01 + x1*M11 + x2*M21);
        float av2 = LAM * (x0*M02 + x1*M12 + x2*M22);
        a2[r][0] = (v2f){av0, av0};
        a2[r][1] = (v2f){av1, av1};
        a2[r][2] = (v2f){av2, av2};
    }

    v2f l2[4];
    v2f acc2[4][DK];
#pragma unroll
    for (int r = 0; r < 4; ++r) {
        l2[r] = (v2f){0.f, 0.f};
#pragma unroll
        for (int d = 0; d < DK; ++d) acc2[r][d] = (v2f){0.f, 0.f};
    }

    const float* KtB = Kt + (size_t)b * 4 * SS;
    const float* VtB = Vt + (size_t)b * DK * SS;

    for (int t = 0; t < SS; t += TK) {
        const bool needVstage = (t <= rowMaxBlk);   // block-uniform
        __syncthreads();
#pragma unroll
        for (int it = 0; it < 4; ++it) {
            int idx = it * NT + tid;
            int d = idx >> 8, c4 = idx & 255;
            GLOAD16(&KtB[(size_t)d * SS + t + c4 * 4], &kls[d][c4 * 4]);
        }
        if (needVstage) {
#pragma unroll
            for (int it = 0; it < 5; ++it) {
                int idx = it * NT + tid;
                int dd = idx >> 8, c4 = idx & 255;
                GLOAD16(&VtB[(size_t)dd * SS + t + c4 * 4], &vls[dd][c4 * 4]);
            }
        }
        __syncthreads();

#pragma unroll
        for (int j = 0; j < TK / 256; ++j) {
            const int key = j * 256 + sub * 4;
            const int cstart = t + j * 256;     // wave-uniform chunk bounds
            const int cend   = cstart + 255;
            const int kbase  = cstart + sub * 4;

            // wide chunk loads: 4 keys per plane, one ds_read_b128 each
            float4 kt0 = *(const float4*)&kls[0][key];
            float4 kt1 = *(const float4*)&kls[1][key];
            float4 kt2 = *(const float4*)&kls[2][key];
            float4 kt3 = *(const float4*)&kls[3][key];

            if (cstart <= hi0 + 1) {
                // V loaded (b128) and consumed in the same scope
                float4 vt0 = *(const float4*)&vls[0][key];
                float4 vt1 = *(const float4*)&vls[1][key];
                float4 vt2 = *(const float4*)&vls[2][key];
                float4 vt3 = *(const float4*)&vls[3][key];
                float4 vt4 = *(const float4*)&vls[4][key];
#pragma unroll
                for (int h = 0; h < 2; ++h) {   // halves = register slices
                    const int kgh = kbase + h * 2;
                    v2f k0 = ((v2f*)&kt0)[h];
                    v2f k1 = ((v2f*)&kt1)[h];
                    v2f k2 = ((v2f*)&kt2)[h];
                    v2f g  = ((v2f*)&kt3)[h];
                    v2f v0 = ((v2f*)&vt0)[h];
                    v2f v1 = ((v2f*)&vt1)[h];
                    v2f v2 = ((v2f*)&vt2)[h];
                    v2f v3 = ((v2f*)&vt3)[h];
                    v2f v4 = ((v2f*)&vt4)[h];
#pragma unroll
                    for (int r = 0; r < 4; ++r) {
                        const int row = rows[r];
                        v2f sc = pk_fma(a2[r][0], k0,
                                 pk_fma(a2[r][1], k1,
                                 pk_fma(a2[r][2], k2, g)));
                        v2f p;
                        p.x = fast_exp2(sc.x); p.y = fast_exp2(sc.y);
                        l2[r] += p;
                        if (cend <= row) {          // full accumulate
                            acc2[r][0] = pk_fma(p, v0, acc2[r][0]);
                            acc2[r][1] = pk_fma(p, v1, acc2[r][1]);
                            acc2[r][2] = pk_fma(p, v2, acc2[r][2]);
                            acc2[r][3] = pk_fma(p, v3, acc2[r][3]);
                            acc2[r][4] = pk_fma(p, v4, acc2[r][4]);
                        } else if (cstart <= row) { // boundary: masked
                            v2f pm;
                            pm.x = (kgh + 0 <= row) ? p.x : 0.f;
                            pm.y = (kgh + 1 <= row) ? p.y : 0.f;
                            acc2[r][0] = pk_fma(pm, v0, acc2[r][0]);
                            acc2[r][1] = pk_fma(pm, v1, acc2[r][1]);
                            acc2[r][2] = pk_fma(pm, v2, acc2[r][2]);
                            acc2[r][3] = pk_fma(pm, v3, acc2[r][3]);
                            acc2[r][4] = pk_fma(pm, v4, acc2[r][4]);
                        }
                        // else: future-only for this row -> denominator only
                    }
                }
            } else {
                // denominator-only chunk for all 4 rows
#pragma unroll
                for (int h = 0; h < 2; ++h) {
                    v2f k0 = ((v2f*)&kt0)[h];
                    v2f k1 = ((v2f*)&kt1)[h];
                    v2f k2 = ((v2f*)&kt2)[h];
                    v2f g  = ((v2f*)&kt3)[h];
#pragma unroll
                    for (int r = 0; r < 4; ++r) {
                        v2f sc = pk_fma(a2[r][0], k0,
                                 pk_fma(a2[r][1], k1,
                                 pk_fma(a2[r][2], k2, g)));
                        v2f p;
                        p.x = fast_exp2(sc.x); p.y = fast_exp2(sc.y);
                        l2[r] += p;
                    }
                }
            }
        }
    }

    // fold packed halves, then butterfly-reduce across the 64 key-split lanes
#pragma unroll
    for (int r = 0; r < 4; ++r) {
        float lr = l2[r].x + l2[r].y;
        float a0 = acc2[r][0].x + acc2[r][0].y;
        float a1 = acc2[r][1].x + acc2[r][1].y;
        float a2_ = acc2[r][2].x + acc2[r][2].y;
        float a3 = acc2[r][3].x + acc2[r][3].y;
        float a4 = acc2[r][4].x + acc2[r][4].y;
#pragma unroll
        for (int off = 32; off >= 1; off >>= 1) {
            lr  += __shfl_xor(lr, off);
            a0  += __shfl_xor(a0, off);
            a1  += __shfl_xor(a1, off);
            a2_ += __shfl_xor(a2_, off);
            a3  += __shfl_xor(a3, off);
            a4  += __shfl_xor(a4, off);
        }
        if (sub < DK) {
            float av = sub == 0 ? a0 : sub == 1 ? a1 : sub == 2 ? a2_ : sub == 3 ? a3 : a4;
            out[((size_t)b * SS + rows[r]) * DK + sub] = av / lr;
        }
    }
}

extern "C" void kernel_launch(void* const* d_in, const int* in_sizes, int n_in,
                              void* d_out, int out_size, void* d_ws, size_t ws_size,
                              hipStream_t stream) {
    const float* x  = (const float*)d_in[0];
    const float* Wq = (const float*)d_in[1];
    const float* bq = (const float*)d_in[2];
    const float* Wk = (const float*)d_in[3];
    const float* Wv = (const float*)d_in[5];
    const float* bv = (const float*)d_in[6];
    float* outp = (float*)d_out;

    float* Kt = (float*)d_ws;                       // [B][4][S]  (x0,x1,x2,g)
    float* Vt = Kt + (size_t)BB * 4 * SS;           // [B][5][S]

    proj_kv<<<(BB * SS + NT - 1) / NT, NT, 0, stream>>>(x, Wk, bq, Wv, bv, Kt, Vt);
    attn<<<BB * (SS / 16), NT, 0, stream>>>(x, Wq, Wk, Kt, Vt, outp);
}

// Round 11
// 28.440 us; speedup vs baseline: 1.5331x; 1.3870x over previous
//
#include <hip/hip_runtime.h>
#include <math.h>

#define BB 4
#define SS 4096
#define DK 5
#define TK 2048
#define NT 256
// (1/sqrt(5)) * log2(e) folded into a' so p = v_exp_f32(score)
#define LAM (0.44721359549995793f * 1.4426950408889634f)

typedef float v2f __attribute__((ext_vector_type(2)));

__device__ __forceinline__ float fast_exp2(float x) {
#if __has_builtin(__builtin_amdgcn_exp2f)
    return __builtin_amdgcn_exp2f(x);
#else
    float r; asm("v_exp_f32 %0, %1" : "=v"(r) : "v"(x)); return r;
#endif
}

// Packed fp32: compiler selects v_pk_fma_f32 on gfx90a+ for <2 x float> fma.
__device__ __forceinline__ v2f pk_fma(v2f a, v2f b, v2f c) {
    return __builtin_elementwise_fma(a, b, c);
}

// async global->LDS, 16B per lane (dest lane-contiguous)
#define GLOAD16(gp, lp)                                                        \
    __builtin_amdgcn_global_load_lds(                                          \
        (const __attribute__((address_space(1))) unsigned int*)(gp),           \
        (__attribute__((address_space(3))) unsigned int*)(lp), 16, 0, 0)

// ---------------------------------------------------------------------------
// Kernel 1: transpose x -> Xt[B][3][S]. That's ALL the preprocessing now:
// the V projection is folded through the attention sum (out = (Wv·Σp x + bv
// Σp)/l), and the bias cross-term is folded into the per-row vector a'.
// ---------------------------------------------------------------------------
__global__ __launch_bounds__(NT) void proj_x(
    const float* __restrict__ x, float* __restrict__ Xt)
{
    int gid = blockIdx.x * NT + threadIdx.x;
    if (gid >= BB * SS) return;
    int b = gid >> 12;
    int s = gid & (SS - 1);
    float* XtB = Xt + (size_t)b * 3 * SS;
    XtB[0 * SS + s] = x[gid * 3 + 0];
    XtB[1 * SS + s] = x[gid * 3 + 1];
    XtB[2 * SS + s] = x[gid * 3 + 2];
}

// ---------------------------------------------------------------------------
// Kernel 2: attention with V folded out of the inner loop.
//   score_rk = a'_r · x_k,  a'_r = LAM*(M^T x_r + Wk^T bq),  M = Wq^T Wk
//   (per-row bias terms cancel in the softmax ratio)
//   acc_r = {Σ_past p·x0, Σ_past p·x1, Σ_past p·x2, Σ_past p},  l_r = Σ_all p
//   out_r,d = (Wv[d]·acc3 + bv[d]·accP)/l_r
// The accumulate's "V operand" IS the k registers already loaded: no Vt, no
// V staging, no V LDS reads. LDS = 3 f32 planes x TK (24 KB). R5 control
// flow: wave = 4 contiguous rows, waves 0,1 low tile / 2,3 mirror high tile.
// ---------------------------------------------------------------------------
__global__ __launch_bounds__(NT, 4) void attn(
    const float* __restrict__ x,
    const float* __restrict__ Wq, const float* __restrict__ bq,
    const float* __restrict__ Wk,
    const float* __restrict__ Wv, const float* __restrict__ bv,
    const float* __restrict__ Xt,
    float* __restrict__ out)
{
    __shared__ float kls[3][TK];

    const int tid = threadIdx.x;
    const int sub = tid & 63;
    const int wave = tid >> 6;

    const int b = blockIdx.x >> 8;
    const int i = blockIdx.x & 255;
    const int lowRow  = i * 8;
    const int highRow = (511 - i) * 8;
    const int row0w = (wave < 2) ? (lowRow + wave * 4) : (highRow + (wave - 2) * 4);

    // M = Wq^T Wk (3x3) and u = Wk^T bq (uniform, cheap once)
    float M00=0,M01=0,M02=0,M10=0,M11=0,M12=0,M20=0,M21=0,M22=0;
    float u0=0,u1=0,u2=0;
#pragma unroll
    for (int d = 0; d < DK; ++d) {
        float q0 = Wq[d*3+0], q1 = Wq[d*3+1], q2 = Wq[d*3+2];
        float k0 = Wk[d*3+0], k1 = Wk[d*3+1], k2 = Wk[d*3+2];
        float bqd = bq[d];
        M00 = fmaf(q0,k0,M00); M01 = fmaf(q0,k1,M01); M02 = fmaf(q0,k2,M02);
        M10 = fmaf(q1,k0,M10); M11 = fmaf(q1,k1,M11); M12 = fmaf(q1,k2,M12);
        M20 = fmaf(q2,k0,M20); M21 = fmaf(q2,k1,M21); M22 = fmaf(q2,k2,M22);
        u0 = fmaf(k0,bqd,u0);  u1 = fmaf(k1,bqd,u1);  u2 = fmaf(k2,bqd,u2);
    }

    // per-row a' (broadcast into both packed halves)
    v2f a2[4][3];
#pragma unroll
    for (int r = 0; r < 4; ++r) {
        const float* xr = &x[((size_t)b * SS + row0w + r) * 3];
        float x0 = xr[0], x1 = xr[1], x2 = xr[2];
        float av0 = LAM * (x0*M00 + x1*M10 + x2*M20 + u0);
        float av1 = LAM * (x0*M01 + x1*M11 + x2*M21 + u1);
        float av2 = LAM * (x0*M02 + x1*M12 + x2*M22 + u2);
        a2[r][0] = (v2f){av0, av0};
        a2[r][1] = (v2f){av1, av1};
        a2[r][2] = (v2f){av2, av2};
    }

    // per-lane epilogue weights (lane sub<5 owns output dim sub)
    float wv0 = 0.f, wv1 = 0.f, wv2 = 0.f, bvl = 0.f;
    if (sub < DK) {
        wv0 = Wv[sub*3+0]; wv1 = Wv[sub*3+1]; wv2 = Wv[sub*3+2]; bvl = bv[sub];
    }

    v2f l2[4];
    v2f acc2[4][4];              // {p*x0, p*x1, p*x2, p} over past keys
#pragma unroll
    for (int r = 0; r < 4; ++r) {
        l2[r] = (v2f){0.f, 0.f};
#pragma unroll
        for (int d = 0; d < 4; ++d) acc2[r][d] = (v2f){0.f, 0.f};
    }

    const float* XtB = Xt + (size_t)b * 3 * SS;

    for (int t = 0; t < SS; t += TK) {
        __syncthreads();
        // stage 3 f32 planes x TK: 1536 slots x 16B, dest lane-contiguous
#pragma unroll
        for (int it = 0; it < 6; ++it) {
            int idx = it * NT + tid;
            int d = idx >> 9, c4 = idx & 511;
            GLOAD16(&XtB[(size_t)d * SS + t + c4 * 4], &kls[d][c4 * 4]);
        }
        __syncthreads();

#pragma unroll
        for (int j = 0; j < TK / 256; ++j) {
            const int key = j * 256 + sub * 4;
            const int cstart = t + j * 256;     // wave-uniform chunk bounds
            const int cend   = cstart + 255;
            const int kbase  = cstart + sub * 4;

            float4 kt0 = *(const float4*)&kls[0][key];
            float4 kt1 = *(const float4*)&kls[1][key];
            float4 kt2 = *(const float4*)&kls[2][key];

            if (cend <= row0w) {
                // ---- full past for all 4 rows ----
#pragma unroll
                for (int h = 0; h < 2; ++h) {
                    v2f k0 = ((v2f*)&kt0)[h];
                    v2f k1 = ((v2f*)&kt1)[h];
                    v2f k2 = ((v2f*)&kt2)[h];
#pragma unroll
                    for (int r = 0; r < 4; ++r) {
                        v2f sc = pk_fma(a2[r][0], k0,
                                 pk_fma(a2[r][1], k1, a2[r][2] * k2));
                        v2f p;
                        p.x = fast_exp2(sc.x); p.y = fast_exp2(sc.y);
                        l2[r] += p;
                        acc2[r][0] = pk_fma(p, k0, acc2[r][0]);
                        acc2[r][1] = pk_fma(p, k1, acc2[r][1]);
                        acc2[r][2] = pk_fma(p, k2, acc2[r][2]);
                        acc2[r][3] += p;
                    }
                }
            } else if (cstart > row0w + 3) {
                // ---- all future: denominator only ----
#pragma unroll
                for (int h = 0; h < 2; ++h) {
                    v2f k0 = ((v2f*)&kt0)[h];
                    v2f k1 = ((v2f*)&kt1)[h];
                    v2f k2 = ((v2f*)&kt2)[h];
#pragma unroll
                    for (int r = 0; r < 4; ++r) {
                        v2f sc = pk_fma(a2[r][0], k0,
                                 pk_fma(a2[r][1], k1, a2[r][2] * k2));
                        v2f p;
                        p.x = fast_exp2(sc.x); p.y = fast_exp2(sc.y);
                        l2[r] += p;
                    }
                }
            } else {
                // ---- boundary chunk (one per wave) ----
#pragma unroll
                for (int h = 0; h < 2; ++h) {
                    const int kgh = kbase + h * 2;
                    v2f k0 = ((v2f*)&kt0)[h];
                    v2f k1 = ((v2f*)&kt1)[h];
                    v2f k2 = ((v2f*)&kt2)[h];
#pragma unroll
                    for (int r = 0; r < 4; ++r) {
                        const int row = row0w + r;
                        v2f sc = pk_fma(a2[r][0], k0,
                                 pk_fma(a2[r][1], k1, a2[r][2] * k2));
                        v2f p;
                        p.x = fast_exp2(sc.x); p.y = fast_exp2(sc.y);
                        l2[r] += p;
                        v2f pm;
                        pm.x = (kgh + 0 <= row) ? p.x : 0.f;
                        pm.y = (kgh + 1 <= row) ? p.y : 0.f;
                        acc2[r][0] = pk_fma(pm, k0, acc2[r][0]);
                        acc2[r][1] = pk_fma(pm, k1, acc2[r][1]);
                        acc2[r][2] = pk_fma(pm, k2, acc2[r][2]);
                        acc2[r][3] += pm;
                    }
                }
            }
        }
    }

    // fold packed halves, butterfly-reduce 5 values across 64 lanes, project
#pragma unroll
    for (int r = 0; r < 4; ++r) {
        float lr = l2[r].x + l2[r].y;
        float A0 = acc2[r][0].x + acc2[r][0].y;
        float A1 = acc2[r][1].x + acc2[r][1].y;
        float A2 = acc2[r][2].x + acc2[r][2].y;
        float PS = acc2[r][3].x + acc2[r][3].y;
#pragma unroll
        for (int off = 32; off >= 1; off >>= 1) {
            lr += __shfl_xor(lr, off);
            A0 += __shfl_xor(A0, off);
            A1 += __shfl_xor(A1, off);
            A2 += __shfl_xor(A2, off);
            PS += __shfl_xor(PS, off);
        }
        if (sub < DK) {
            float num = fmaf(wv0, A0, fmaf(wv1, A1, fmaf(wv2, A2, bvl * PS)));
            out[((size_t)b * SS + row0w + r) * DK + sub] = num / lr;
        }
    }
}

extern "C" void kernel_launch(void* const* d_in, const int* in_sizes, int n_in,
                              void* d_out, int out_size, void* d_ws, size_t ws_size,
                              hipStream_t stream) {
    const float* x  = (const float*)d_in[0];
    const float* Wq = (const float*)d_in[1];
    const float* bq = (const float*)d_in[2];
    const float* Wk = (const float*)d_in[3];
    const float* Wv = (const float*)d_in[5];
    const float* bv = (const float*)d_in[6];
    float* outp = (float*)d_out;

    float* Xt = (float*)d_ws;                       // [B][3][S] f32 (196 KB)

    proj_x<<<(BB * SS + NT - 1) / NT, NT, 0, stream>>>(x, Xt);
    attn<<<BB * (SS / 16), NT, 0, stream>>>(x, Wq, bq, Wk, Wv, bv, Xt, outp);
}